// Round 15
// baseline (361.834 us; speedup 1.0000x reference)
//
#include <hip/hip_runtime.h>
#include <hip/hip_bf16.h>

typedef __attribute__((ext_vector_type(8))) short short8;   // 8 bf16 (4 VGPRs)
typedef __attribute__((ext_vector_type(4))) float f32x4;    // MFMA 16x16 C/D
typedef __attribute__((ext_vector_type(16))) float f32x16;  // MFMA 32x32 C/D

#define NB 8
#define NC 256
#define NN 4096
#define ND 32
#define NCH 16    // j-chunks of 256
#define LDP 264   // P row stride in ushorts (256+8 pad): base+imm LDS addressing
#define LOG2E 1.44269504088896340736f

static __device__ __forceinline__ ushort f2bf(float f) {
  __hip_bfloat16 h = __float2bfloat16(f);
  return reinterpret_cast<ushort&>(h);
}

// ---------------------------------------------------------------------------
// Projection (unchanged): fp32 MAC, bf16 out; Q pre-scaled by log2(e).
//   blockIdx.y==0 : o in [0,64)  -> QK[b][n][64]  (q 0..31, k 32..63)
//   blockIdx.y>=1 : o in [64,320)-> Vt[b][o-64][n]  (V transposed, bf16)
// ---------------------------------------------------------------------------
__global__ __launch_bounds__(256, 4)
void proj_kernel(const float* __restrict__ x,
                 const float* __restrict__ wq, const float* __restrict__ bq,
                 const float* __restrict__ wk, const float* __restrict__ bk,
                 const float* __restrict__ wv, const float* __restrict__ bv,
                 ushort* __restrict__ qk, ushort* __restrict__ vt) {
  __shared__ float Xs[16][128];
  __shared__ float Ws[16][64];
  const int n0 = blockIdx.x * 128;
  const int o0 = blockIdx.y * 64;
  const int b  = blockIdx.z;
  const int t  = threadIdx.x;
  const int og4 = t & 15;
  const int ng  = t >> 4;

  float acc[4][8];
#pragma unroll
  for (int i = 0; i < 4; ++i)
#pragma unroll
    for (int j = 0; j < 8; ++j) acc[i][j] = 0.f;

  const int xs_r = t >> 4;
  const int xs_c = (t & 15) * 4;
  const int ws_o = t & 63;
  const int ws_c = (t >> 6) * 4;
  const float* wrow;
  {
    const int o = o0 + ws_o;
    if (o < 32)      wrow = wq + (size_t)o * NC;
    else if (o < 64) wrow = wk + (size_t)(o - 32) * NC;
    else             wrow = wv + (size_t)(o - 64) * NC;
  }

  for (int c0 = 0; c0 < NC; c0 += 16) {
    __syncthreads();
    const float* xsrc = x + ((size_t)(b * NC + c0 + xs_r)) * NN + n0;
    *(float4*)&Xs[xs_r][xs_c]      = *(const float4*)(xsrc + xs_c);
    *(float4*)&Xs[xs_r][64 + xs_c] = *(const float4*)(xsrc + 64 + xs_c);
    {
      const float4 wv4 = *(const float4*)(wrow + c0 + ws_c);
      Ws[ws_c + 0][ws_o] = wv4.x;
      Ws[ws_c + 1][ws_o] = wv4.y;
      Ws[ws_c + 2][ws_o] = wv4.z;
      Ws[ws_c + 3][ws_o] = wv4.w;
    }
    __syncthreads();
#pragma unroll
    for (int cc = 0; cc < 16; ++cc) {
      const float4 wv4 = *(const float4*)&Ws[cc][og4 * 4];
      const float4 xa  = *(const float4*)&Xs[cc][ng * 8];
      const float4 xb  = *(const float4*)&Xs[cc][ng * 8 + 4];
      const float wvv[4] = {wv4.x, wv4.y, wv4.z, wv4.w};
      const float xaa[8] = {xa.x, xa.y, xa.z, xa.w, xb.x, xb.y, xb.z, xb.w};
#pragma unroll
      for (int i = 0; i < 4; ++i)
#pragma unroll
        for (int j = 0; j < 8; ++j) acc[i][j] += wvv[i] * xaa[j];
    }
  }

  if (blockIdx.y == 0) {
    float bb[4], sc[4];
#pragma unroll
    for (int i = 0; i < 4; ++i) {
      const int o = og4 * 4 + i;
      bb[i] = (o < 32) ? bq[o] : bk[o - 32];
      sc[i] = (o < 32) ? LOG2E : 1.0f;
    }
#pragma unroll
    for (int j = 0; j < 8; ++j) {
      union { ushort u[4]; uint2 v; } pk;
#pragma unroll
      for (int i = 0; i < 4; ++i) pk.u[i] = f2bf((acc[i][j] + bb[i]) * sc[i]);
      *(uint2*)(qk + ((size_t)(b * NN + n0 + ng * 8 + j)) * 64 + og4 * 4) = pk.v;
    }
  } else {
#pragma unroll
    for (int i = 0; i < 4; ++i) {
      const int c = o0 - 64 + og4 * 4 + i;
      const float bb = bv[c];
      union { ushort u[8]; uint4 v; } pk;
#pragma unroll
      for (int j = 0; j < 8; ++j) pk.u[j] = f2bf(acc[i][j] + bb);
      *(uint4*)(vt + ((size_t)(b * NC + c)) * NN + n0 + ng * 8) = pk.v;
    }
  }
}

// ---------------------------------------------------------------------------
// Flash attention: R10 producer/consumer structure, VALU-addressing removed.
// 256 blocks x 512 threads. Block = (b, 128 q-rows). j-chunk 256, 17
// intervals, ONE barrier each. P dbuf [2][128][264] LINEAR (padded) so every
// LDS access is base-reg + compile-time immediate offset (no per-access XOR
// arithmetic; ~96 accesses/wave/chunk drop ~5 VALU each). ~4-way bank
// aliasing on b128 reads accepted (R6-measured, ~9% of wall worst case).
//  Waves 0-3 (S): rows w*32..+32: swapped mfma16(K,Q), exp2 (Q pre-scaled),
//    TRUNCATING bf16 pack (2 ops/value), b64 P writes at imm offsets.
//    kf[8] single buffer: compute half0 -> load half1 (one exposed stall) ->
//    compute half1 -> prefetch half0(c+1) (drains at barrier under PV).
//  Waves 4-7 (PV): consume P[(iv-1)&1]: 64 ch/wave, 32x32x16 MFMA
//    (OA/OB = 128 AGPR); V inline (2 loads per 8 MFMAs, L2-resident).
// Register frame identical to R10 (VGPR ~124 + AGPR 128 = 252): no spill.
// ---------------------------------------------------------------------------
#define S_JT(KF, COL)                                                         \
  do {                                                                        \
    const f32x4 s0 = __builtin_amdgcn_mfma_f32_16x16x32_bf16(KF, qf0, zero,   \
                                                             0, 0, 0);        \
    const f32x4 s1 = __builtin_amdgcn_mfma_f32_16x16x32_bf16(KF, qf1, zero,   \
                                                             0, 0, 0);        \
    const uint a0 = __builtin_bit_cast(uint, exp2f(s0[0])) & 0xFFFF0000u;     \
    const uint a1 = __builtin_bit_cast(uint, exp2f(s0[1])) & 0xFFFF0000u;     \
    const uint a2 = __builtin_bit_cast(uint, exp2f(s0[2])) & 0xFFFF0000u;     \
    const uint a3 = __builtin_bit_cast(uint, exp2f(s0[3])) & 0xFFFF0000u;     \
    const uint b0 = __builtin_bit_cast(uint, exp2f(s1[0])) & 0xFFFF0000u;     \
    const uint b1 = __builtin_bit_cast(uint, exp2f(s1[1])) & 0xFFFF0000u;     \
    const uint b2 = __builtin_bit_cast(uint, exp2f(s1[2])) & 0xFFFF0000u;     \
    const uint b3 = __builtin_bit_cast(uint, exp2f(s1[3])) & 0xFFFF0000u;     \
    lp0 += (__builtin_bit_cast(float, a0) + __builtin_bit_cast(float, a1)) +  \
           (__builtin_bit_cast(float, a2) + __builtin_bit_cast(float, a3));   \
    lp1 += (__builtin_bit_cast(float, b0) + __builtin_bit_cast(float, b1)) +  \
           (__builtin_bit_cast(float, b2) + __builtin_bit_cast(float, b3));   \
    uint2 w0, w1;                                                             \
    w0.x = (a0 >> 16) | a1;  w0.y = (a2 >> 16) | a3;                          \
    w1.x = (b0 >> 16) | b1;  w1.y = (b2 >> 16) | b3;                          \
    *(uint2*)(pw0 + (COL)) = w0;                                              \
    *(uint2*)(pw1 + (COL)) = w1;                                              \
  } while (0)

#define KLOAD(KF, J0)                                                         \
  do {                                                                        \
    _Pragma("unroll")                                                         \
    for (int jt = 0; jt < 8; ++jt)                                            \
      KF[jt] = *(const short8*)(kbase + (size_t)((J0) + jt * 16 + c16) * 64); \
  } while (0)

// PV: one 16-j step: 2 V loads + 8 mfma32; P reads at imm offsets off pr0..3.
#define PV_STEP(JO)                                                           \
  do {                                                                        \
    const short8 vf0 = *(const short8*)(vbA + j0 + (JO));                     \
    const short8 vf1 = *(const short8*)(vbB + j0 + (JO));                     \
    const short8 p0 = *(const short8*)(pr0 + (JO));                           \
    const short8 p1 = *(const short8*)(pr1 + (JO));                           \
    const short8 p2 = *(const short8*)(pr2 + (JO));                           \
    const short8 p3 = *(const short8*)(pr3 + (JO));                           \
    OA[0] = __builtin_amdgcn_mfma_f32_32x32x16_bf16(p0, vf0, OA[0], 0, 0, 0); \
    OB[0] = __builtin_amdgcn_mfma_f32_32x32x16_bf16(p0, vf1, OB[0], 0, 0, 0); \
    OA[1] = __builtin_amdgcn_mfma_f32_32x32x16_bf16(p1, vf0, OA[1], 0, 0, 0); \
    OB[1] = __builtin_amdgcn_mfma_f32_32x32x16_bf16(p1, vf1, OB[1], 0, 0, 0); \
    OA[2] = __builtin_amdgcn_mfma_f32_32x32x16_bf16(p2, vf0, OA[2], 0, 0, 0); \
    OB[2] = __builtin_amdgcn_mfma_f32_32x32x16_bf16(p2, vf1, OB[2], 0, 0, 0); \
    OA[3] = __builtin_amdgcn_mfma_f32_32x32x16_bf16(p3, vf0, OA[3], 0, 0, 0); \
    OB[3] = __builtin_amdgcn_mfma_f32_32x32x16_bf16(p3, vf1, OB[3], 0, 0, 0); \
  } while (0)

__global__ __launch_bounds__(512, 1)
void attn_kernel(const ushort* __restrict__ qk, const ushort* __restrict__ vt,
                 const float* __restrict__ x, const float* __restrict__ gamma,
                 float* __restrict__ out) {
  __shared__ __align__(16) ushort P[2][128 * LDP];   // 135168 B, linear+pad
  __shared__ __align__(16) float lL[128];

  const int lin  = blockIdx.x;
  const int b    = lin & 7;              // XCD swizzle: batch per XCD L2
  const int i0   = (lin >> 3) * 128;
  const int t    = threadIdx.x;
  const int w    = t >> 6;               // 0..7
  const int lane = t & 63;
  const int g16  = lane >> 4;
  const int c16  = lane & 15;
  const int l5   = lane >> 5;
  const int c32  = lane & 31;

  const f32x4 zero = {0.f, 0.f, 0.f, 0.f};
  const bool isS = (w < 4);

  // ---- S state (waves 0-3): 32 q-rows each ----
  const int prow0 = w * 32 + c16;
  const int prow1 = prow0 + 16;
  short8 qf0, qf1;
  short8 kf[8];
  float lp0 = 0.f, lp1 = 0.f;
  const ushort* kbase = qk + ((size_t)b * NN) * 64 + 32 + g16 * 8;
  if (isS) {
    qf0 = *(const short8*)(qk + ((size_t)(b * NN + i0 + prow0)) * 64 + g16 * 8);
    qf1 = *(const short8*)(qk + ((size_t)(b * NN + i0 + prow1)) * 64 + g16 * 8);
    KLOAD(kf, 0);   // prologue: half0 of chunk 0
  }

  // ---- PV state (waves 4-7): 64 channels each ----
  const int p = w - 4;
  f32x16 OA[4], OB[4];
  const ushort* vbA = nullptr; const ushort* vbB = nullptr;
  if (!isS) {
#pragma unroll
    for (int isub = 0; isub < 4; ++isub)
#pragma unroll
      for (int e = 0; e < 16; ++e) { OA[isub][e] = 0.f; OB[isub][e] = 0.f; }
    vbA = vt + ((size_t)(b * NC + p * 64 + c32)) * NN + l5 * 8;
    vbB = vt + ((size_t)(b * NC + p * 64 + 32 + c32)) * NN + l5 * 8;
  }

  for (int iv = 0; iv <= NCH; ++iv) {
    if (isS) {
      if (iv < NCH) {
        const int j0 = iv * 256;
        // per-row write bases (buffer-dependent; 2 cheap adds per chunk)
        ushort* pw0 = &P[iv & 1][prow0 * LDP + g16 * 4];
        ushort* pw1 = &P[iv & 1][prow1 * LDP + g16 * 4];
        // compute half0 (kf prefetched last interval)
        S_JT(kf[0], 0);   S_JT(kf[1], 16);  S_JT(kf[2], 32);  S_JT(kf[3], 48);
        S_JT(kf[4], 64);  S_JT(kf[5], 80);  S_JT(kf[6], 96);  S_JT(kf[7], 112);
        // load half1 (one exposed stall), compute it
        KLOAD(kf, j0 + 128);
        S_JT(kf[0], 128); S_JT(kf[1], 144); S_JT(kf[2], 160); S_JT(kf[3], 176);
        S_JT(kf[4], 192); S_JT(kf[5], 208); S_JT(kf[6], 224); S_JT(kf[7], 240);
        // prefetch half0 of next chunk; drains at the barrier while PV runs
        if (iv + 1 < NCH) KLOAD(kf, j0 + 256);
      } else {
        // interval 16: finalize row sums (reduce over the 4 g16 groups)
        lp0 += __shfl_xor(lp0, 16); lp0 += __shfl_xor(lp0, 32);
        lp1 += __shfl_xor(lp1, 16); lp1 += __shfl_xor(lp1, 32);
        if (g16 == 0) { lL[prow0] = lp0; lL[prow1] = lp1; }
      }
    } else if (iv >= 1) {
      const int ch = iv - 1;
      const int j0 = ch * 256;
      // per-isub read bases (buffer-dependent; imm offsets for all 64 reads)
      const ushort* pr0 = &P[ch & 1][(0 * 32 + c32) * LDP + l5 * 8];
      const ushort* pr1 = &P[ch & 1][(1 * 32 + c32) * LDP + l5 * 8];
      const ushort* pr2 = &P[ch & 1][(2 * 32 + c32) * LDP + l5 * 8];
      const ushort* pr3 = &P[ch & 1][(3 * 32 + c32) * LDP + l5 * 8];
      __builtin_amdgcn_s_setprio(1);
      PV_STEP(0);   PV_STEP(16);  PV_STEP(32);  PV_STEP(48);
      PV_STEP(64);  PV_STEP(80);  PV_STEP(96);  PV_STEP(112);
      PV_STEP(128); PV_STEP(144); PV_STEP(160); PV_STEP(176);
      PV_STEP(192); PV_STEP(208); PV_STEP(224); PV_STEP(240);
      __builtin_amdgcn_s_setprio(0);
    }
    __syncthreads();
  }

  // ---- epilogue: PV waves write out = gamma*O/l + x ----
  if (!isS) {
    const float g = gamma[0];
#pragma unroll
    for (int isub = 0; isub < 4; ++isub) {
#pragma unroll
      for (int q = 0; q < 4; ++q) {
        const int r0 = isub * 32 + q * 8 + l5 * 4;   // D row: (reg&3)+8q+4*l5
        const f32x4 li = *(const f32x4*)&lL[r0];
        f32x4 gi;
#pragma unroll
        for (int r = 0; r < 4; ++r) gi[r] = g / li[r];
        {
          const int c = p * 64 + c32;
          const size_t base = ((size_t)(b * NC + c)) * NN + i0 + r0;
          const f32x4 xv = *(const f32x4*)(x + base);
          f32x4 ov;
#pragma unroll
          for (int r = 0; r < 4; ++r) ov[r] = OA[isub][q * 4 + r] * gi[r] + xv[r];
          *(f32x4*)(out + base) = ov;
        }
        {
          const int c = p * 64 + 32 + c32;
          const size_t base = ((size_t)(b * NC + c)) * NN + i0 + r0;
          const f32x4 xv = *(const f32x4*)(x + base);
          f32x4 ov;
#pragma unroll
          for (int r = 0; r < 4; ++r) ov[r] = OB[isub][q * 4 + r] * gi[r] + xv[r];
          *(f32x4*)(out + base) = ov;
        }
      }
    }
  }
}

extern "C" void kernel_launch(void* const* d_in, const int* in_sizes, int n_in,
                              void* d_out, int out_size, void* d_ws, size_t ws_size,
                              hipStream_t stream) {
  const float* x  = (const float*)d_in[0];
  const float* wq = (const float*)d_in[1];
  const float* bq = (const float*)d_in[2];
  const float* wk = (const float*)d_in[3];
  const float* bk = (const float*)d_in[4];
  const float* wv = (const float*)d_in[5];
  const float* bv = (const float*)d_in[6];
  const float* gm = (const float*)d_in[7];
  float* outp = (float*)d_out;

  ushort* qkw = (ushort*)d_ws;                       // [B][N][64]  bf16, 4 MB
  ushort* vtw = qkw + (size_t)NB * NN * 64;          // [B][C][N]   bf16, 16 MB

  proj_kernel<<<dim3(NN / 128, 5, NB), 256, 0, stream>>>(
      x, wq, bq, wk, bk, wv, bv, qkw, vtw);
  attn_kernel<<<dim3((NN / 128) * NB), 512, 0, stream>>>(qkw, vtw, x, gm, outp);
}

// Round 16
// 150.564 us; speedup vs baseline: 2.4032x; 2.4032x over previous
//
#include <hip/hip_runtime.h>
#include <hip/hip_bf16.h>

typedef __attribute__((ext_vector_type(8))) short short8;   // 8 bf16 (4 VGPRs)
typedef __attribute__((ext_vector_type(4))) float f32x4;    // MFMA 16x16 C/D
typedef __attribute__((ext_vector_type(16))) float f32x16;  // MFMA 32x32 C/D

#define NB 8
#define NC 256
#define NN 4096
#define ND 32
#define NCH 16   // attn j-chunks of 256
#define LOG2E 1.44269504088896340736f

// attn P tile [2][128][256] ushort, 16B-slot XOR swizzle (validated R8/R10).
#define PIDX(row, col) (((row) << 8) + ((col) ^ (((row) & 15) << 3)))

static __device__ __forceinline__ ushort f2bf(float f) {
  __hip_bfloat16 h = __float2bfloat16(f);
  return reinterpret_cast<ushort&>(h);
}
static __device__ __forceinline__ float bf2f(ushort u) {
  const uint v = ((uint)u) << 16;
  return __builtin_bit_cast(float, v);
}

// ---------------------------------------------------------------------------
// Projection via MFMA (bf16, W hi/lo split for ~fp32 weight precision).
// Block = (128-n tile, 64-o tile, b); 256 thr / 4 waves; K-chunks of 32.
//   o in [0,64)  -> QK[b][n][64]  (q rows pre-scaled by log2e)
//   o in [64,320)-> Vt[b][o-64][n]
// Ws: [2][64][264] bf16 (hi/lo of W, padded).  Xs: [32 c][...] transposed to
// [n][c] at stride 40 ushorts (80 B: 16B-aligned b128 B-frag reads).
// Per chunk per wave: 8 nt x 2 (hi+lo) = 16 mfma16; acc = 8 x f32x4.
// vt epilogue bounces through Ws[0] (reused as Os[64][136]) for coalesced
// uint4 global stores.
// ---------------------------------------------------------------------------
#define LDW 264   // Ws row stride (ushorts)
#define LDX 40    // Xs row stride (ushorts) -> 80 B rows, 16B-aligned
#define LDO 136   // Os row stride (ushorts)

__global__ __launch_bounds__(256, 2)
void proj_kernel(const float* __restrict__ x,
                 const float* __restrict__ wq, const float* __restrict__ bq,
                 const float* __restrict__ wk, const float* __restrict__ bk,
                 const float* __restrict__ wv, const float* __restrict__ bv,
                 ushort* __restrict__ qk, ushort* __restrict__ vt) {
  __shared__ __align__(16) ushort Ws[2][64 * LDW];   // 67.6 KB
  __shared__ __align__(16) ushort Xs[128 * LDX];     // 10.2 KB

  const int n0 = blockIdx.x * 128;
  const int o0 = blockIdx.y * 64;
  const int b  = blockIdx.z;
  const int t  = threadIdx.x;
  const int w  = t >> 6;
  const int lane = t & 63;
  const int g16  = lane >> 4;
  const int c16  = lane & 15;

  // ---- stage W tile [64 o][256 c] as bf16 hi + lo ----
  {
    const int o  = t >> 2;          // 0..63
    const int cb = (t & 3) * 64;    // 64 c per thread
    const int oa = o0 + o;
    const float* wrow;
    float scale = 1.0f;
    if (oa < 32)       { wrow = wq + (size_t)oa * NC; scale = LOG2E; }
    else if (oa < 64)  { wrow = wk + (size_t)(oa - 32) * NC; }
    else               { wrow = wv + (size_t)(oa - 64) * NC; }
#pragma unroll
    for (int cc = 0; cc < 64; cc += 8) {
      const float4 f0 = *(const float4*)(wrow + cb + cc);
      const float4 f1 = *(const float4*)(wrow + cb + cc + 4);
      float v[8] = {f0.x, f0.y, f0.z, f0.w, f1.x, f1.y, f1.z, f1.w};
      union { ushort u[8]; uint4 q; } hi, lo;
#pragma unroll
      for (int e = 0; e < 8; ++e) {
        const float s = v[e] * scale;
        const ushort h = f2bf(s);
        hi.u[e] = h;
        lo.u[e] = f2bf(s - bf2f(h));
      }
      *(uint4*)&Ws[0][o * LDW + cb + cc] = hi.q;
      *(uint4*)&Ws[1][o * LDW + cb + cc] = lo.q;
    }
  }

  f32x4 acc[8];
#pragma unroll
  for (int nt = 0; nt < 8; ++nt)
#pragma unroll
    for (int r = 0; r < 4; ++r) acc[nt][r] = 0.f;

  // staging coords: wave w stages c-rows w*8..+8; lane covers 4 n, 4 iters
  const int s_cc = w * 8 + (lane >> 3);
  const int s_nb = (lane & 7) * 4;

  for (int c0 = 0; c0 < NC; c0 += 32) {
    __syncthreads();   // previous compute done; Xs free
    {
      const float* xsrc = x + ((size_t)(b * NC + c0 + s_cc)) * NN + n0 + s_nb;
#pragma unroll
      for (int it = 0; it < 4; ++it) {
        const float4 f = *(const float4*)(xsrc + it * 32);
        const int n = s_nb + it * 32;
        Xs[(n + 0) * LDX + s_cc] = f2bf(f.x);
        Xs[(n + 1) * LDX + s_cc] = f2bf(f.y);
        Xs[(n + 2) * LDX + s_cc] = f2bf(f.z);
        Xs[(n + 3) * LDX + s_cc] = f2bf(f.w);
      }
    }
    __syncthreads();   // Xs ready

    const short8 ah = *(const short8*)&Ws[0][(w * 16 + c16) * LDW + c0 + g16 * 8];
    const short8 al = *(const short8*)&Ws[1][(w * 16 + c16) * LDW + c0 + g16 * 8];
#pragma unroll
    for (int nt = 0; nt < 8; ++nt) {
      const short8 bf = *(const short8*)&Xs[(nt * 16 + c16) * LDX + g16 * 8];
      acc[nt] = __builtin_amdgcn_mfma_f32_16x16x32_bf16(ah, bf, acc[nt], 0, 0, 0);
      acc[nt] = __builtin_amdgcn_mfma_f32_16x16x32_bf16(al, bf, acc[nt], 0, 0, 0);
    }
  }

  // D layout: row o = w*16 + g16*4 + r, col n = n0 + nt*16 + c16
  if (blockIdx.y == 0) {
    float bb[4];
#pragma unroll
    for (int r = 0; r < 4; ++r) {
      const int o = w * 16 + g16 * 4 + r;
      bb[r] = (o < 32) ? bq[o] * LOG2E : bk[o - 32];
    }
#pragma unroll
    for (int nt = 0; nt < 8; ++nt) {
      union { ushort u[4]; uint2 v; } pk;
#pragma unroll
      for (int r = 0; r < 4; ++r) pk.u[r] = f2bf(acc[nt][r] + bb[r]);
      const int n = n0 + nt * 16 + c16;
      *(uint2*)(qk + ((size_t)(b * NN + n)) * 64 + w * 16 + g16 * 4) = pk.v;
    }
  } else {
    const int ch0 = o0 - 64;
    float bb[4];
#pragma unroll
    for (int r = 0; r < 4; ++r) bb[r] = bv[ch0 + w * 16 + g16 * 4 + r];
    __syncthreads();   // all waves done reading Ws; reuse Ws[0] as Os[64][136]
    ushort* Os = &Ws[0][0];
#pragma unroll
    for (int nt = 0; nt < 8; ++nt) {
#pragma unroll
      for (int r = 0; r < 4; ++r)
        Os[(w * 16 + g16 * 4 + r) * LDO + nt * 16 + c16] =
            f2bf(acc[nt][r] + bb[r]);
    }
    __syncthreads();
    // coalesced store: thread -> ch = t>>2, 32 n at (t&3)*32
    const int chl = t >> 2;
    const int nb  = (t & 3) * 32;
    ushort* dst = vt + ((size_t)(b * NC + ch0 + chl)) * NN + n0 + nb;
#pragma unroll
    for (int k = 0; k < 4; ++k)
      *(uint4*)(dst + k * 8) = *(const uint4*)&Os[chl * LDO + nb + k * 8];
  }
}

// ---------------------------------------------------------------------------
// Flash attention — R10 VERBATIM (best measured: 148 us, no spill).
// Producer/consumer wave specialization, 256 blocks x 512 threads.
// ---------------------------------------------------------------------------
__global__ __launch_bounds__(512, 1)
void attn_kernel(const ushort* __restrict__ qk, const ushort* __restrict__ vt,
                 const float* __restrict__ x, const float* __restrict__ gamma,
                 float* __restrict__ out) {
  __shared__ __align__(16) ushort P[2][128 * 256];   // 128 KB, swizzled
  __shared__ __align__(16) float lL[128];

  const int lin  = blockIdx.x;
  const int b    = lin & 7;              // XCD swizzle: batch per XCD L2
  const int i0   = (lin >> 3) * 128;
  const int t    = threadIdx.x;
  const int w    = t >> 6;               // 0..7
  const int lane = t & 63;
  const int g16  = lane >> 4;
  const int c16  = lane & 15;
  const int l5   = lane >> 5;
  const int c32  = lane & 31;

  const f32x4 zero = {0.f, 0.f, 0.f, 0.f};
  const bool isS = (w < 4);

  // ---- S state (waves 0-3) ----
  const int prow0 = w * 32 + c16;
  const int prow1 = prow0 + 16;
  short8 qf0, qf1;
  short8 kf[8];
  float lp0 = 0.f, lp1 = 0.f;
  const ushort* kbase = qk + ((size_t)b * NN) * 64 + 32 + g16 * 8;
  if (isS) {
    qf0 = *(const short8*)(qk + ((size_t)(b * NN + i0 + prow0)) * 64 + g16 * 8);
    qf1 = *(const short8*)(qk + ((size_t)(b * NN + i0 + prow1)) * 64 + g16 * 8);
  }

  // ---- PV state (waves 4-7) ----
  const int p = w - 4;
  f32x16 OA[4], OB[4];
  const ushort* vbA = nullptr; const ushort* vbB = nullptr;
  if (!isS) {
#pragma unroll
    for (int isub = 0; isub < 4; ++isub)
#pragma unroll
      for (int e = 0; e < 16; ++e) { OA[isub][e] = 0.f; OB[isub][e] = 0.f; }
    vbA = vt + ((size_t)(b * NC + p * 64 + c32)) * NN + l5 * 8;
    vbB = vt + ((size_t)(b * NC + p * 64 + 32 + c32)) * NN + l5 * 8;
  }

  for (int iv = 0; iv <= NCH; ++iv) {
    if (isS) {
      if (iv < NCH) {
        ushort* Pb = P[iv & 1];
        const ushort* kch = kbase + (size_t)iv * 256 * 64;
#pragma unroll
        for (int h = 0; h < 2; ++h) {
#pragma unroll
          for (int jt = 0; jt < 8; ++jt)
            kf[jt] = *(const short8*)(
                kch + (size_t)(h * 128 + jt * 16 + c16) * 64);
#pragma unroll
          for (int jt = 0; jt < 8; ++jt) {
            const f32x4 s0 = __builtin_amdgcn_mfma_f32_16x16x32_bf16(
                kf[jt], qf0, zero, 0, 0, 0);
            const f32x4 s1 = __builtin_amdgcn_mfma_f32_16x16x32_bf16(
                kf[jt], qf1, zero, 0, 0, 0);
            union { ushort u[4]; uint2 v; } pk0, pk1;
#pragma unroll
            for (int r = 0; r < 4; ++r) {
              const float e0 = exp2f(s0[r]);
              const float e1 = exp2f(s1[r]);
              lp0 += e0; lp1 += e1;
              pk0.u[r] = f2bf(e0); pk1.u[r] = f2bf(e1);
            }
            const int col = h * 128 + jt * 16 + g16 * 4;
            *(uint2*)&Pb[PIDX(prow0, col)] = pk0.v;
            *(uint2*)&Pb[PIDX(prow1, col)] = pk1.v;
          }
        }
      } else {
        lp0 += __shfl_xor(lp0, 16); lp0 += __shfl_xor(lp0, 32);
        lp1 += __shfl_xor(lp1, 16); lp1 += __shfl_xor(lp1, 32);
        if (g16 == 0) { lL[prow0] = lp0; lL[prow1] = lp1; }
      }
    } else if (iv >= 1) {
      const int ch = iv - 1;
      const ushort* Pb = P[ch & 1];
      const int j0 = ch * 256;
      __builtin_amdgcn_s_setprio(1);
#pragma unroll
      for (int ji = 0; ji < 16; ++ji) {
        const int jo = ji * 16;
        const short8 vf0 = *(const short8*)(vbA + j0 + jo);
        const short8 vf1 = *(const short8*)(vbB + j0 + jo);
#pragma unroll
        for (int isub = 0; isub < 4; ++isub) {
          const short8 pa =
              *(const short8*)&Pb[PIDX(isub * 32 + c32, jo + l5 * 8)];
          OA[isub] = __builtin_amdgcn_mfma_f32_32x32x16_bf16(
              pa, vf0, OA[isub], 0, 0, 0);
          OB[isub] = __builtin_amdgcn_mfma_f32_32x32x16_bf16(
              pa, vf1, OB[isub], 0, 0, 0);
        }
      }
      __builtin_amdgcn_s_setprio(0);
    }
    __syncthreads();
  }

  // ---- epilogue: PV waves write out = gamma*O/l + x ----
  if (!isS) {
    const float g = gamma[0];
#pragma unroll
    for (int isub = 0; isub < 4; ++isub) {
#pragma unroll
      for (int q = 0; q < 4; ++q) {
        const int r0 = isub * 32 + q * 8 + l5 * 4;   // D row: (reg&3)+8q+4*l5
        const f32x4 li = *(const f32x4*)&lL[r0];
        f32x4 gi;
#pragma unroll
        for (int r = 0; r < 4; ++r) gi[r] = g / li[r];
        {
          const int c = p * 64 + c32;
          const size_t base = ((size_t)(b * NC + c)) * NN + i0 + r0;
          const f32x4 xv = *(const f32x4*)(x + base);
          f32x4 ov;
#pragma unroll
          for (int r = 0; r < 4; ++r) ov[r] = OA[isub][q * 4 + r] * gi[r] + xv[r];
          *(f32x4*)(out + base) = ov;
        }
        {
          const int c = p * 64 + 32 + c32;
          const size_t base = ((size_t)(b * NC + c)) * NN + i0 + r0;
          const f32x4 xv = *(const f32x4*)(x + base);
          f32x4 ov;
#pragma unroll
          for (int r = 0; r < 4; ++r) ov[r] = OB[isub][q * 4 + r] * gi[r] + xv[r];
          *(f32x4*)(out + base) = ov;
        }
      }
    }
  }
}

extern "C" void kernel_launch(void* const* d_in, const int* in_sizes, int n_in,
                              void* d_out, int out_size, void* d_ws, size_t ws_size,
                              hipStream_t stream) {
  const float* x  = (const float*)d_in[0];
  const float* wq = (const float*)d_in[1];
  const float* bq = (const float*)d_in[2];
  const float* wk = (const float*)d_in[3];
  const float* bk = (const float*)d_in[4];
  const float* wv = (const float*)d_in[5];
  const float* bv = (const float*)d_in[6];
  const float* gm = (const float*)d_in[7];
  float* outp = (float*)d_out;

  ushort* qkw = (ushort*)d_ws;                       // [B][N][64]  bf16, 4 MB
  ushort* vtw = qkw + (size_t)NB * NN * 64;          // [B][C][N]   bf16, 16 MB

  proj_kernel<<<dim3(NN / 128, 5, NB), 256, 0, stream>>>(
      x, wq, bq, wk, bk, wv, bv, qkw, vtw);
  attn_kernel<<<dim3((NN / 128) * NB), 512, 0, stream>>>(qkw, vtw, x, gm, outp);
}